// Round 11
// baseline (512.189 us; speedup 1.0000x reference)
//
#include <hip/hip_runtime.h>
#include <hip/hip_bf16.h>
#include <math.h>

#define N_NODES 16384
#define DIMV 1024
#define NHEADS 16
#define HEADD 64

typedef __attribute__((ext_vector_type(8))) short short8;
typedef __attribute__((ext_vector_type(4))) float f32x4;
typedef unsigned short ushort_t;

// async global->LDS, 16B per lane
#define GLD16(gptr, lptr)                                                                 \
  __builtin_amdgcn_global_load_lds((const __attribute__((address_space(1))) void*)(gptr), \
                                   (__attribute__((address_space(3))) void*)(lptr), 16, 0, 0)

#define SCHED0() __builtin_amdgcn_sched_barrier(0)
#define SBAR() __builtin_amdgcn_s_barrier()
#define DSREAD(dst, addr) \
  asm volatile("ds_read_b128 %0, %1" : "=v"(dst) : "v"(addr) : "memory")
#define WAITLGKM0() asm volatile("s_waitcnt lgkmcnt(0)" ::: "memory")
#define VM_IMPL(n) asm volatile("s_waitcnt vmcnt(" #n ")" ::: "memory")
#define VM(n) VM_IMPL(n)

__device__ __forceinline__ unsigned lds_base_addr(const void* p) {
  return (unsigned)(uintptr_t)(const __attribute__((address_space(3))) void*)p;
}

// ---------- helpers ----------

__device__ __forceinline__ float waveReduceSum(float v) {
#pragma unroll
  for (int m = 32; m; m >>= 1) v += __shfl_xor(v, m);
  return v;
}

__device__ __forceinline__ float blockReduceSum(float v, float* red) {
  float w = waveReduceSum(v);
  __syncthreads();
  if ((threadIdx.x & 63) == 0) red[threadIdx.x >> 6] = w;
  __syncthreads();
  return red[0] + red[1] + red[2] + red[3];
}

__device__ __forceinline__ float elup1(float z) {
  return z > 0.0f ? z + 1.0f : expm1f(z) + 1.0f;
}

__device__ __forceinline__ float clampabs(float x, float eps) {
  float s = (x >= 0.0f) ? 1.0f : -1.0f;
  return s * fmaxf(fabsf(x), eps);
}

// fp32 -> bf16 bits, RNE
__device__ __forceinline__ ushort_t f2b(float x) {
  unsigned u = __float_as_uint(x);
  unsigned r = (u + 0x7FFFu + ((u >> 16) & 1u)) >> 16;
  return (ushort_t)r;
}
__device__ __forceinline__ float b2f(ushort_t h) {
  return __uint_as_float(((unsigned)h) << 16);
}

// ---------- X -> bf16 + row sumsq (one block per row) ----------
__global__ __launch_bounds__(256) void cvt_norm_kernel(const float* __restrict__ src,
                                                       ushort_t* __restrict__ dst,
                                                       float* __restrict__ rowsq) {
  __shared__ float red[4];
  const int row = blockIdx.x;
  const int t = threadIdx.x;
  float4 x4 = ((const float4*)(src + (size_t)row * DIMV))[t];
  ushort_t h[4] = {f2b(x4.x), f2b(x4.y), f2b(x4.z), f2b(x4.w)};
  ((uint2*)(dst + (size_t)row * DIMV))[t] = *(uint2*)h;
  float s = x4.x * x4.x + x4.y * x4.y + x4.z * x4.z + x4.w * x4.w;
  s = blockReduceSum(s, red);
  if (t == 0) rowsq[row] = s;
}

// ---------- weight transpose -> bf16 (hi, and optional lo residual) ----------
template <bool LO>
__global__ __launch_bounds__(256) void transW_kernel(const float* __restrict__ src,
                                                     ushort_t* __restrict__ hi,
                                                     ushort_t* __restrict__ lo) {
  __shared__ float tile[32][33];
  const int bx = blockIdx.x * 32, by = blockIdx.y * 32;
  const int tx = threadIdx.x & 31, ty = threadIdx.x >> 5;
#pragma unroll
  for (int i = 0; i < 32; i += 8) tile[ty + i][tx] = src[(size_t)(by + ty + i) * DIMV + bx + tx];
  __syncthreads();
#pragma unroll
  for (int i = 0; i < 32; i += 8) {
    float v = tile[tx][ty + i];
    ushort_t h = f2b(v);
    hi[(size_t)(bx + ty + i) * DIMV + by + tx] = h;
    if (LO) lo[(size_t)(bx + ty + i) * DIMV + by + tx] = f2b(v - b2f(h));
  }
}

// k-unit swizzle (16B units within a 64B row, r8-verified): LDS[row][u] = global unit
// u ^ ((row>>1)&3). Staging thread t: row=t>>2, unit=t&3, src unit = (t&3)^((t>>3)&3).
// Fragment read: unit (lane>>4) of row (base16+l15) at unit (lane>>4)^((lane>>1)&3)
// -> 2 lanes/bank (free).

// ---------- bf16 MFMA GEMM: 256x256, BK=32, 8 waves, 4-buf ring, 8-phase-style ----------
// Per K-tile (32k): 4 phases. Phase q = {2 A-frag ds_reads (+4 B-frag at q=0, reg-held);
// stage 1 half-tile of K-tile j+3; vmcnt(9+q); s_barrier; lgkm(0); setprio; 8 MFMA;
// setprio; s_barrier}. Stage-3-ahead, vmcnt never 0 mid-loop (T4); 2 barriers/phase make
// the stage->read hazard safe. LDS 128 KB = 4 bufs x (A 16KB + B 16KB).
// EPI 0: Cq = bf16(acc); EPI 3: QK fused (v1 / v2+v2sum). Coalesced epilogue via LDS.
template <int EPI, int NB>
__global__ __launch_bounds__(512, 2) void gemm_bf(const ushort_t* __restrict__ A,
                                                  const ushort_t* __restrict__ Bt,
                                                  const float* __restrict__ biasQ,
                                                  const float* __restrict__ biasK,
                                                  const float* __restrict__ denom,
                                                  const float* __restrict__ mask,
                                                  float* __restrict__ v2sum,
                                                  ushort_t* __restrict__ Cq,
                                                  ushort_t* __restrict__ Ck) {
  __shared__ ushort_t LB[65536];  // 128 KB
  char* LBc = (char*)LB;
  const int bid = blockIdx.x;
  const int nwg = NB * 64;
  const int swz = (bid & 7) * (nwg / 8) + (bid >> 3);
  const int bm = (swz / NB) * 256;
  const int bn = (swz % NB) * 256;
  const int t = threadIdx.x;
  const int w = t >> 6, lane = t & 63, l15 = lane & 15;
  const int wr = (w >> 2) * 128;   // wave row base (2 M-groups of 128)
  const int wcn = (w & 3) * 64;    // wave col base (4 N-groups of 64)
  const int ah = w >> 2;           // wave's A half
  const int bh = (w & 3) >> 1;     // wave's B half
  const int brow = (w & 1) * 64;   // B local row base within half
  const unsigned kswz = (((lane >> 4) ^ ((lane >> 1) & 3)) << 4);  // frag unit byte off
  const int srck = (((t & 3) ^ ((t >> 3) & 3)) << 3);              // staging src k-elems

  // staging sources (1 GLD16 per thread per half-tile unit)
  const ushort_t* gA0 = A + (size_t)(bm + (t >> 2)) * DIMV + srck;
  const ushort_t* gA1 = gA0 + (size_t)128 * DIMV;
  const ushort_t* gB0 = Bt + (size_t)(bn + (t >> 2)) * DIMV + srck;
  const ushort_t* gB1 = gB0 + (size_t)128 * DIMV;

  const unsigned lbase = lds_base_addr(LB);

  f32x4 acc[8][4];
#pragma unroll
  for (int i = 0; i < 8; ++i)
#pragma unroll
    for (int j = 0; j < 4; ++j) acc[i][j] = (f32x4){0.f, 0.f, 0.f, 0.f};

  // prologue: stage K-tiles 0,1,2 (12 loads/thread); retire tile 0 (8 younger allowed)
#pragma unroll
  for (int j = 0; j < 3; ++j) {
    char* sd = LBc + j * 32768;
    GLD16(gA0 + j * 32, sd + t * 16);
    GLD16(gA1 + j * 32, sd + 8192 + t * 16);
    GLD16(gB0 + j * 32, sd + 16384 + t * 16);
    GLD16(gB1 + j * 32, sd + 24576 + t * 16);
  }
  SCHED0();
  VM(8);
  SBAR();
  SCHED0();

  short8 af0, af1, bf0, bf1, bf2, bf3;

#define PHASE(q, ab, bb, SRC, DOFF, DOSTAGE, sd, ko, VN)                                      \
  {                                                                                           \
    DSREAD(af0, (ab) + ((q) * 32 + l15) * 64 + kswz);                                         \
    DSREAD(af1, (ab) + ((q) * 32 + 16 + l15) * 64 + kswz);                                    \
    if ((q) == 0) {                                                                           \
      DSREAD(bf0, (bb) + (brow + l15) * 64 + kswz);                                           \
      DSREAD(bf1, (bb) + (brow + 16 + l15) * 64 + kswz);                                      \
      DSREAD(bf2, (bb) + (brow + 32 + l15) * 64 + kswz);                                      \
      DSREAD(bf3, (bb) + (brow + 48 + l15) * 64 + kswz);                                      \
    }                                                                                         \
    if (DOSTAGE) GLD16((SRC) + (ko), (sd) + (DOFF) + t * 16);                                 \
    SCHED0();                                                                                 \
    VM(VN);                                                                                   \
    SBAR();                                                                                   \
    WAITLGKM0();                                                                              \
    SCHED0();                                                                                 \
    __builtin_amdgcn_s_setprio(1);                                                            \
    acc[2 * (q)][0] = __builtin_amdgcn_mfma_f32_16x16x32_bf16(af0, bf0, acc[2 * (q)][0], 0, 0, 0); \
    acc[2 * (q)][1] = __builtin_amdgcn_mfma_f32_16x16x32_bf16(af0, bf1, acc[2 * (q)][1], 0, 0, 0); \
    acc[2 * (q)][2] = __builtin_amdgcn_mfma_f32_16x16x32_bf16(af0, bf2, acc[2 * (q)][2], 0, 0, 0); \
    acc[2 * (q)][3] = __builtin_amdgcn_mfma_f32_16x16x32_bf16(af0, bf3, acc[2 * (q)][3], 0, 0, 0); \
    acc[2 * (q) + 1][0] = __builtin_amdgcn_mfma_f32_16x16x32_bf16(af1, bf0, acc[2 * (q) + 1][0], 0, 0, 0); \
    acc[2 * (q) + 1][1] = __builtin_amdgcn_mfma_f32_16x16x32_bf16(af1, bf1, acc[2 * (q) + 1][1], 0, 0, 0); \
    acc[2 * (q) + 1][2] = __builtin_amdgcn_mfma_f32_16x16x32_bf16(af1, bf2, acc[2 * (q) + 1][2], 0, 0, 0); \
    acc[2 * (q) + 1][3] = __builtin_amdgcn_mfma_f32_16x16x32_bf16(af1, bf3, acc[2 * (q) + 1][3], 0, 0, 0); \
    __builtin_amdgcn_s_setprio(0);                                                            \
    SCHED0();                                                                                 \
    SBAR();                                                                                   \
  }

#define TILE(j, DOSTAGE, VA, VB, VC, VD)                                 \
  {                                                                      \
    const unsigned ab = lbase + ((j) & 3) * 32768u + (unsigned)ah * 8192u; \
    const unsigned bb = lbase + ((j) & 3) * 32768u + 16384u + (unsigned)bh * 8192u; \
    char* sd = LBc + (((j) + 3) & 3) * 32768;                            \
    const int ko = ((j) + 3) * 32;                                       \
    PHASE(0, ab, bb, gA0, 0, DOSTAGE, sd, ko, VA)                        \
    PHASE(1, ab, bb, gA1, 8192, DOSTAGE, sd, ko, VB)                     \
    PHASE(2, ab, bb, gB0, 16384, DOSTAGE, sd, ko, VC)                    \
    PHASE(3, ab, bb, gB1, 24576, DOSTAGE, sd, ko, VD)                    \
  }

  for (int j = 0; j < 29; ++j) TILE(j, 1, 9, 10, 11, 12);
  TILE(29, 0, 8, 8, 8, 8);
  TILE(30, 0, 4, 4, 4, 4);
  TILE(31, 0, 0, 0, 0, 0);
#undef TILE
#undef PHASE

  // ---- epilogue: math -> LDS [128][256] bf16 -> coalesced global stores, 2 passes ----
  const int rbase = (lane >> 4) * 4;
  const int prow = w >> 2;
  const bool isK = (EPI == 3) && (bn >= DIMV);
  const int h = ((bn + wcn) >> 6) & (NHEADS - 1);
  ushort_t* dst = (EPI == 3 && isK) ? Ck : Cq;
  const int coloff = (EPI == 3) ? (bn & (DIMV - 1)) : bn;
  float bb2[4];
#pragma unroll
  for (int j = 0; j < 4; ++j)
    bb2[j] = (EPI == 3) ? (isK ? biasK[(bn + wcn + j * 16 + l15) & (DIMV - 1)]
                               : biasQ[(bn + wcn + j * 16 + l15) & (DIMV - 1)])
                        : 0.0f;
  float csum[4] = {0.f, 0.f, 0.f, 0.f};

  __syncthreads();
#pragma unroll
  for (int p = 0; p < 2; ++p) {
    if (prow == p) {
#pragma unroll
      for (int i = 0; i < 8; ++i) {
#pragma unroll
        for (int r = 0; r < 4; ++r) {
          const int row_l = i * 16 + rbase + r;
          float invdp = 1.0f, den = 0.f, mk = 0.f;
          if (EPI == 3) {
            invdp = 1.0f / denom[(size_t)h * N_NODES + bm + p * 128 + row_l];
            if (isK) {
              den = clampabs(2.0f * invdp - 1.0f, 1e-10f);
              mk = mask[bm + p * 128 + row_l];
            }
          }
#pragma unroll
          for (int j = 0; j < 4; ++j) {
            float val = acc[i][j][r];
            if (EPI == 3) {
              val = elup1((val + bb2[j]) * invdp);
              if (isK) {
                val = den * val * mk;
                csum[j] += val;
              }
            }
            LB[row_l * 256 + wcn + j * 16 + l15] = f2b(val);
          }
        }
      }
    }
    __syncthreads();
#pragma unroll
    for (int it = 0; it < 8; ++it) {
      const int idx = it * 512 + t;
      const int row_l = idx >> 5, cq = idx & 31;
      uint4 v = *(const uint4*)&LB[row_l * 256 + cq * 8];
      *(uint4*)(dst + (size_t)(bm + p * 128 + row_l) * DIMV + coloff + cq * 8) = v;
    }
    __syncthreads();
  }
  if (EPI == 3 && isK) {
#pragma unroll
    for (int j = 0; j < 4; ++j)
      atomicAdd(&v2sum[(bn + wcn + j * 16 + l15) & (DIMV - 1)], csum[j]);
  }
}

// ---------- fused 3-term split GEMM: C = bf16(AhiBhi + AloBhi + AhiBlo) ----------
// 256x256 tile, BK=32, 8 waves, dbuf, swizzled LDS, coalesced epilogue. 128 KB LDS.
__global__ __launch_bounds__(512, 2) void gemm_split3(const ushort_t* __restrict__ Ahi,
                                                      const ushort_t* __restrict__ Alo,
                                                      const ushort_t* __restrict__ Bhi,
                                                      const ushort_t* __restrict__ Blo,
                                                      ushort_t* __restrict__ C) {
  __shared__ ushort_t LB[65536];  // AH:0 AL:16384 BH:32768 BL:49152, each [2][8192]
  const int bid = blockIdx.x;
  const int swz = (bid & 7) * 32 + (bid >> 3);  // nwg = 256
  const int bm = (swz >> 2) * 256;
  const int bn = (swz & 3) * 256;
  const int t = threadIdx.x;
  const int w = t >> 6, lane = t & 63, l15 = lane & 15;
  const int wr = (w >> 2) * 128;
  const int wcn = (w & 3) * 64;
  const int kks = (((lane >> 4) ^ ((lane >> 1) & 3)) << 3);
  const int sksw = (((lane & 3) ^ ((lane >> 3) & 3)) << 3);

  size_t goA[2], goB[2];
  int lofs[2];
#pragma unroll
  for (int c = 0; c < 2; ++c) {
    const int ch = w + 8 * c;
    lofs[c] = ch * 512 + lane * 8;
    goA[c] = (size_t)(bm + ch * 16 + (lane >> 2)) * DIMV + sksw;
    goB[c] = (size_t)(bn + ch * 16 + (lane >> 2)) * DIMV + sksw;
  }

#define STAGE_S(buf, k0)                                             \
  do {                                                               \
    _Pragma("unroll") for (int c = 0; c < 2; ++c) {                  \
      GLD16(Ahi + goA[c] + (k0), &LB[(buf)*8192 + lofs[c]]);         \
      GLD16(Alo + goA[c] + (k0), &LB[16384 + (buf)*8192 + lofs[c]]); \
      GLD16(Bhi + goB[c] + (k0), &LB[32768 + (buf)*8192 + lofs[c]]); \
      GLD16(Blo + goB[c] + (k0), &LB[49152 + (buf)*8192 + lofs[c]]); \
    }                                                                \
  } while (0)

  f32x4 acc[8][4];
#pragma unroll
  for (int i = 0; i < 8; ++i)
#pragma unroll
    for (int j = 0; j < 4; ++j) acc[i][j] = (f32x4){0.f, 0.f, 0.f, 0.f};

  STAGE_S(0, 0);
  __syncthreads();
  int cur = 0;
  for (int k0 = 0; k0 < DIMV; k0 += 32) {
    if (k0 + 32 < DIMV) STAGE_S(cur ^ 1, k0 + 32);
    short8 bfH[4], bfL[4];
#pragma unroll
    for (int j = 0; j < 4; ++j) {
      bfH[j] = *(const short8*)&LB[32768 + cur * 8192 + (wcn + j * 16 + l15) * 32 + kks];
      bfL[j] = *(const short8*)&LB[49152 + cur * 8192 + (wcn + j * 16 + l15) * 32 + kks];
    }
#pragma unroll
    for (int i = 0; i < 8; ++i) {
      short8 afH = *(const short8*)&LB[cur * 8192 + (wr + i * 16 + l15) * 32 + kks];
      short8 afL = *(const short8*)&LB[16384 + cur * 8192 + (wr + i * 16 + l15) * 32 + kks];
#pragma unroll
      for (int j = 0; j < 4; ++j) {
        acc[i][j] = __builtin_amdgcn_mfma_f32_16x16x32_bf16(afH, bfH[j], acc[i][j], 0, 0, 0);
        acc[i][j] = __builtin_amdgcn_mfma_f32_16x16x32_bf16(afL, bfH[j], acc[i][j], 0, 0, 0);
        acc[i][j] = __builtin_amdgcn_mfma_f32_16x16x32_bf16(afH, bfL[j], acc[i][j], 0, 0, 0);
      }
    }
    __syncthreads();
    cur ^= 1;
  }
#undef STAGE_S

  // coalesced epilogue via LDS [128][256] (reuses first 64KB)
  const int rbase = (lane >> 4) * 4;
  const int prow = w >> 2;
#pragma unroll
  for (int p = 0; p < 2; ++p) {
    if (prow == p) {
#pragma unroll
      for (int i = 0; i < 8; ++i)
#pragma unroll
        for (int r = 0; r < 4; ++r) {
          const int row_l = i * 16 + rbase + r;
#pragma unroll
          for (int j = 0; j < 4; ++j)
            LB[row_l * 256 + wcn + j * 16 + l15] = f2b(acc[i][j][r]);
        }
    }
    __syncthreads();
#pragma unroll
    for (int it = 0; it < 8; ++it) {
      const int idx = it * 512 + t;
      const int row_l = idx >> 5, cq = idx & 31;
      uint4 v = *(const uint4*)&LB[row_l * 256 + cq * 8];
      *(uint4*)(C + (size_t)(bm + p * 128 + row_l) * DIMV + bn + cq * 8) = v;
    }
    __syncthreads();
  }
}

// ---------- row transform: mobius_matvec tail + kappa_relu (bf16 msrc, precomputed ||x||^2) ----------
template <bool BFDST>
__global__ __launch_bounds__(256) void rowtrans_kernel(const ushort_t* __restrict__ msrc,
                                                       const float* __restrict__ rowsq,
                                                       void* __restrict__ dstv,
                                                       float* __restrict__ denom) {
  __shared__ float red[4];
  __shared__ float orow[DIMV];
  const int row = blockIdx.x;
  const int t = threadIdx.x;
  uint2 mraw = ((const uint2*)(msrc + (size_t)row * DIMV))[t];
  ushort_t* mh = (ushort_t*)&mraw;
  float4 m4 = make_float4(b2f(mh[0]), b2f(mh[1]), b2f(mh[2]), b2f(mh[3]));
  float sm = m4.x * m4.x + m4.y * m4.y + m4.z * m4.z + m4.w * m4.w;
  sm = blockReduceSum(sm, red);
  float sx = rowsq[row];

  float xn = fmaxf(sqrtf(sx), 1e-15f);
  float mxn = fmaxf(sqrtf(sm), 1e-15f);
  float cx = fminf(xn, 1.0f - 1e-7f);
  float t1 = tanhf(mxn / xn * atanhf(cx));
  float s1 = t1 / mxn;

  float yn = fmaxf(fabsf(t1), 1e-15f);
  float a = atanhf(fminf(yn, 1.0f - 1e-7f)) / yn;
  float k1 = a * s1;
  float4 u = make_float4(fmaxf(k1 * m4.x, 0.0f), fmaxf(k1 * m4.y, 0.0f),
                         fmaxf(k1 * m4.z, 0.0f), fmaxf(k1 * m4.w, 0.0f));
  float su = u.x * u.x + u.y * u.y + u.z * u.z + u.w * u.w;
  su = blockReduceSum(su, red);

  float un = fmaxf(sqrtf(su), 1e-15f);
  float t2 = tanhf(un);
  float s2 = t2 / un;
  if (t2 > 0.996f) s2 *= 0.996f / t2;
  float4 o = make_float4(s2 * u.x, s2 * u.y, s2 * u.z, s2 * u.w);
  if (BFDST) {
    ushort_t h[4] = {f2b(o.x), f2b(o.y), f2b(o.z), f2b(o.w)};
    ((uint2*)((ushort_t*)dstv + (size_t)row * DIMV))[t] = *(uint2*)h;
  } else {
    ((float4*)((float*)dstv + (size_t)row * DIMV))[t] = o;
  }

  if (denom) {
    ((float4*)orow)[t] = o;
    __syncthreads();
    if (t < NHEADS) {
      float s = 0.0f;
#pragma unroll
      for (int i = 0; i < HEADD; ++i) {
        float v = orow[t * HEADD + i];
        s = fmaf(v, v, s);
      }
      denom[t * N_NODES + row] = fmaxf(1.0f - s, 1e-15f);
    }
  }
}

// ---------- ctxT[h][e][d] = sum_n v2[h,n,d] * (gamma/den * mask * V)[h,n,e]  (v2,V bf16) ----------
__global__ __launch_bounds__(256) void context_kernel(const ushort_t* __restrict__ v2buf,
                                                      const ushort_t* __restrict__ vbuf,
                                                      const float* __restrict__ denom,
                                                      const float* __restrict__ mask,
                                                      float* __restrict__ ctxT) {
  __shared__ float s2[64][65];
  __shared__ float sx[64][65];
  const int h = blockIdx.y;
  const int t = threadIdx.x;
  const int d0 = (t >> 4) * 4;
  const int e0 = (t & 15) * 4;
  float acc[4][4];
#pragma unroll
  for (int i = 0; i < 4; ++i)
#pragma unroll
    for (int j = 0; j < 4; ++j) acc[i][j] = 0.0f;

  const int rbase = blockIdx.x * 512;
  for (int c = 0; c < 8; ++c) {
#pragma unroll
    for (int i = 0; i < 4; ++i) {
      int f = i * 256 + t;
      int r = f >> 4;
      int cc = (f & 15) * 4;
      int row = rbase + c * 64 + r;
      uint2 araw = *(const uint2*)(v2buf + (size_t)row * DIMV + h * HEADD + cc);
      ushort_t* ah = (ushort_t*)&araw;
      s2[r][cc + 0] = b2f(ah[0]); s2[r][cc + 1] = b2f(ah[1]);
      s2[r][cc + 2] = b2f(ah[2]); s2[r][cc + 3] = b2f(ah[3]);
      float dp = denom[(size_t)h * N_NODES + row];
      float gamma = 2.0f / dp;
      float den = clampabs(gamma - 1.0f, 1e-10f);
      float c1 = gamma / den * mask[row];
      uint2 braw = *(const uint2*)(vbuf + (size_t)row * DIMV + h * HEADD + cc);
      ushort_t* bh = (ushort_t*)&braw;
      sx[r][cc + 0] = c1 * b2f(bh[0]); sx[r][cc + 1] = c1 * b2f(bh[1]);
      sx[r][cc + 2] = c1 * b2f(bh[2]); sx[r][cc + 3] = c1 * b2f(bh[3]);
    }
    __syncthreads();
    for (int r = 0; r < 64; ++r) {
      float av[4], bv[4];
#pragma unroll
      for (int i = 0; i < 4; ++i) av[i] = s2[r][d0 + i];
#pragma unroll
      for (int j = 0; j < 4; ++j) bv[j] = sx[r][e0 + j];
#pragma unroll
      for (int i = 0; i < 4; ++i)
#pragma unroll
        for (int j = 0; j < 4; ++j) acc[i][j] = fmaf(av[i], bv[j], acc[i][j]);
    }
    __syncthreads();
  }
#pragma unroll
  for (int i = 0; i < 4; ++i)
#pragma unroll
    for (int j = 0; j < 4; ++j)
      atomicAdd(&ctxT[h * 4096 + (e0 + j) * 64 + (d0 + i)], acc[i][j]);
}

// ---------- out (MFMA): [out|D] = v1 @ [ctx|v2sum]; tail; emit combHi/Lo + rownorm atomics ----------
__global__ __launch_bounds__(256) void out_mfma_kernel(const ushort_t* __restrict__ v1bf,
                                                       const float* __restrict__ v2sum,
                                                       const float* __restrict__ ctxT,
                                                       ushort_t* __restrict__ combHi,
                                                       ushort_t* __restrict__ combLo,
                                                       float* __restrict__ combnorm) {
  __shared__ ushort_t Blds[80][88];
  const int h = blockIdx.y;
  const int bm = blockIdx.x * 256;
  const int t = threadIdx.x;
  const int w = t >> 6, lane = t & 63, l15 = lane & 15;
  const int kk = (lane >> 4) * 8;

  for (int idx = t; idx < 80 * 64; idx += 256) {
    int e = idx >> 6, d = idx & 63;
    float v = 0.0f;
    if (e < 64) v = ctxT[h * 4096 + e * 64 + d];
    else if (e == 64) v = v2sum[h * 64 + d];
    Blds[e][d] = f2b(v);
  }
  __syncthreads();

  f32x4 acc[4][5];
#pragma unroll
  for (int i = 0; i < 4; ++i)
#pragma unroll
    for (int j = 0; j < 5; ++j) acc[i][j] = (f32x4){0.f, 0.f, 0.f, 0.f};
#pragma unroll
  for (int ks = 0; ks < 2; ++ks) {
    short8 bfr[5];
#pragma unroll
    for (int j = 0; j < 5; ++j) bfr[j] = *(const short8*)&Blds[j * 16 + l15][ks * 32 + kk];
#pragma unroll
    for (int i = 0; i < 4; ++i) {
      short8 af = *(const short8*)(v1bf + (size_t)(bm + w * 64 + i * 16 + l15) * DIMV +
                                   h * HEADD + ks * 32 + kk);
#pragma unroll
      for (int j = 0; j < 5; ++j)
        acc[i][j] = __builtin_amdgcn_mfma_f32_16x16x32_bf16(af, bfr[j], acc[i][j], 0, 0, 0);
    }
  }

  const int g4 = (lane >> 4) * 4;
#pragma unroll
  for (int i = 0; i < 4; ++i) {
#pragma unroll
    for (int r = 0; r < 4; ++r) {
      const int row = bm + w * 64 + i * 16 + g4 + r;
      float D = __shfl(acc[i][4][r], lane & 48);
      float Dinv = 1.0f / (D == 0.0f ? 1e-5f : D);
      float o[4];
      float s = 0.0f;
#pragma unroll
      for (int j = 0; j < 4; ++j) {
        o[j] = acc[i][j][r] * Dinv;
        s = fmaf(o[j], o[j], s);
      }
      s += __shfl_xor(s, 1); s += __shfl_xor(s, 2);
      s += __shfl_xor(s, 4); s += __shfl_xor(s, 8);
      float n1 = fmaxf(sqrtf(s), 1e-15f);
      float sc = 1.0f;
      if (n1 > 0.996f) sc = 0.996f / n1;
      float xn = fmaxf(fminf(n1, 0.996f), 1e-15f);
      float cx = fminf(xn, 1.0f - 1e-7f);
      float t2 = tanhf(0.5f * atanhf(cx));
      sc *= t2 / xn;
      if (t2 > 0.996f) sc *= 0.996f / t2;
      if (l15 == 0) atomicAdd(&combnorm[row], s * sc * sc);
#pragma unroll
      for (int j = 0; j < 4; ++j) {
        float ov = o[j] * sc;
        size_t off = (size_t)row * DIMV + h * HEADD + j * 16 + l15;
        ushort_t hi = f2b(ov);
        combHi[off] = hi;
        combLo[off] = f2b(ov - b2f(hi));
      }
    }
  }
}

// ---------- launch ----------

extern "C" void kernel_launch(void* const* d_in, const int* in_sizes, int n_in,
                              void* d_out, int out_size, void* d_ws, size_t ws_size,
                              hipStream_t stream) {
  const float* X = (const float*)d_in[0];
  const float* mask = (const float*)d_in[1];
  const float* Wq = (const float*)d_in[2];
  const float* bq = (const float*)d_in[3];
  const float* Wk = (const float*)d_in[4];
  const float* bk = (const float*)d_in[5];
  const float* Wv = (const float*)d_in[6];
  const float* Wff = (const float*)d_in[7];
  float* out = (float*)d_out;

  const size_t MAT = (size_t)N_NODES * DIMV;
  char* p = (char*)d_ws;
  // R1 (64MB): first half v1bf (QK epi out); second half mxV bf16, later combnorm
  ushort_t* v1bf = (ushort_t*)p;
  ushort_t* mxV = (ushort_t*)(p + MAT * 2);
  float* combnorm = (float*)(p + MAT * 2);
  p += MAT * 4;
  // R2 (64MB): xnormsq (early) / v2bf (QK epi out) / combHi+combLo (after context)
  float* xnormsq = (float*)p;
  ushort_t* v2bf = (ushort_t*)p;
  ushort_t* combHi = (ushort_t*)p;
  ushort_t* combLo = combHi + MAT;
  p += MAT * 4;
  // R3 (32MB): Vbf; later WffHi/WffLo
  ushort_t* Vbf = (ushort_t*)p;
  ushort_t* WffHi = Vbf;
  ushort_t* WffLo = Vbf + (size_t)DIMV * DIMV;
  p += MAT * 2;
  // R4 (32MB): Xbf; later outBf (split3 out)
  ushort_t* Xbf = (ushort_t*)p;
  ushort_t* outBf = Xbf;
  p += MAT * 2;
  float* denom = (float*)p;  p += (size_t)NHEADS * N_NODES * 4;
  float* v2sum = (float*)p;  p += 1024 * 4;
  float* ctxT = (float*)p;   p += (size_t)NHEADS * 4096 * 4;
  const size_t need = (size_t)(p - (char*)d_ws);
  if (ws_size < need) return;

  // W^T bf16 scratch inside d_out (free until the final rowtrans writes it):
  ushort_t* Wt = (ushort_t*)d_out;            // Wv^T, later Wq^T (rows 0..1023)
  ushort_t* WtK = Wt + (size_t)DIMV * DIMV;   // Wk^T (rows 1024..2047 of stacked QK)

  dim3 tgrid(32, 32);

  cvt_norm_kernel<<<N_NODES, 256, 0, stream>>>(X, Xbf, xnormsq);
  // V path: mxV bf16, then rowtrans -> Vbf + denom
  transW_kernel<false><<<tgrid, 256, 0, stream>>>(Wv, Wt, nullptr);
  gemm_bf<0, 4><<<256, 512, 0, stream>>>(Xbf, Wt, nullptr, nullptr, nullptr, nullptr,
                                         nullptr, mxV, nullptr);
  rowtrans_kernel<true><<<N_NODES, 256, 0, stream>>>(mxV, xnormsq, Vbf, denom);
  // zero accumulators (v2sum+ctxT contiguous; combnorm over dead mxV)
  hipMemsetAsync(v2sum, 0, (1024 + 4096 * NHEADS) * sizeof(float), stream);
  hipMemsetAsync(combnorm, 0, N_NODES * sizeof(float), stream);
  // QK fused: stacked [Wq^T; Wk^T], epilogue emits v1 (cols<1024) and v2 + v2sum (cols>=1024)
  transW_kernel<false><<<tgrid, 256, 0, stream>>>(Wq, Wt, nullptr);
  transW_kernel<false><<<tgrid, 256, 0, stream>>>(Wk, WtK, nullptr);
  gemm_bf<3, 8><<<512, 512, 0, stream>>>(Xbf, Wt, bq, bk, denom, mask, v2sum, v1bf, v2bf);
  // context (transposed output)
  context_kernel<<<dim3(32, NHEADS), 256, 0, stream>>>(v2bf, Vbf, denom, mask, ctxT);
  // attention out -> combHi/Lo + row norms
  out_mfma_kernel<<<dim3(N_NODES / 256, NHEADS), 256, 0, stream>>>(v1bf, v2sum, ctxT, combHi,
                                                                   combLo, combnorm);
  // final: fused 3-term split GEMM -> outBf, then rowtrans -> d_out
  transW_kernel<true><<<tgrid, 256, 0, stream>>>(Wff, WffHi, WffLo);
  gemm_split3<<<256, 512, 0, stream>>>(combHi, combLo, WffHi, WffLo, outBf);
  rowtrans_kernel<false><<<N_NODES, 256, 0, stream>>>(outBf, combnorm, out, nullptr);
}